// Round 5
// baseline (307.838 us; speedup 1.0000x reference)
//
#include <hip/hip_runtime.h>

// x: (64, 4, 2, 256, 256) f32 ; tensors: (4,4,128,128,2,2,2,2,2) f32 ;
// bias: (4,128,128,2) f32 ; out: (64,4,2,128,128) f32
// sx=sy=256 even -> ix1=2x+1, iy1=2y+1 (clamp inert).
#define NUMN 64
#define CIN 4
#define COUT 4
#define SX 256
#define SY 256
#define NXX 128
#define NYY 128
#define YTILE 32
#define NSPLIT 2
#define NPER (NUMN / NSPLIT)

// R9: NO LDS, NO BARRIERS. R4/R7/R8 all land 86-88us regardless of barrier
// flavor -> the stage+sync structure itself is the stall, not the fence.
// Key fact: each thread's inputs are pairwise contiguous in global memory:
//   (a,e) = x[n,c,d, 2xi  , 2y..2y+1]  -> one aligned float2
//   (b,f) = x[n,c,d, 2xi+1, 2y..2y+1]  -> one aligned float2
// Lanes yl=0..31 read CONSECUTIVE float2s (256B segment per wave request),
// and lanes 32-63 (other o) read the same addresses (TA coalescer dedups).
// So direct global float2 loads are already perfectly coalesced; the LDS
// round-trip (ds_write -> barrier -> 16x ds_read, wave-lockstepped) was pure
// overhead. Without barriers the compiler schedules loads freely across
// iterations; the 8x po-redundancy per block is absorbed by L1/L2 (per-XCD
// L2 trivially holds the 4KB/iter working set even if waves drift).
// Expected VGPR ~115 (wr 64 + ld 32 + addr/misc) -> 4 waves/SIMD at (256,2)
// without spill risk. If VGPR_Count > 128 next round caps it.
__global__ __launch_bounds__(256, 2)
void ttn_kernel(const float* __restrict__ x, const float* __restrict__ w,
                const float* __restrict__ bias, float* __restrict__ out)
{
    const int bid = blockIdx.x;
    const int xi = bid % NXX;
    const int yt = (bid / NXX) % (NYY / YTILE);
    const int ns = bid / (NXX * (NYY / YTILE));

    const int tid = threadIdx.x;
    const int yl  = tid & (YTILE - 1);
    const int po  = tid >> 5;                    // p*2 + o  (0..7)
    const int p   = po >> 1;
    const int o   = po & 1;
    const int y   = yt * YTILE + yl;

    // ---- weight preamble: wr[c][q], q = 8i+4j+2k+l (float4 loads) ----
    float wr[CIN][16];
#pragma unroll
    for (int c = 0; c < CIN; ++c) {
        const float4* wp4 = (const float4*)(w +
            ((size_t)(((c * COUT + p) * NXX + xi) * NYY + y)) * 32);
#pragma unroll
        for (int j = 0; j < 8; ++j) {
            const float4 v = wp4[j];
            wr[c][2 * j]     = o ? v.y : v.x;
            wr[c][2 * j + 1] = o ? v.w : v.z;
        }
    }
    const float bv = bias[(((p * NXX + xi) * NYY + y) * 2) + o];

    const size_t nstr = (size_t)CIN * 2 * SX * SY;
    const size_t ostr = (size_t)COUT * 2 * NXX * NYY;

    // per-lane x pointer at (n = ns*NPER, c=0, d=0, row 2xi, col 2y)
    const float* xp = x + (size_t)(ns * NPER) * nstr
                        + (size_t)(2 * xi) * SY + 2 * y;
    float* ob = out + (size_t)(ns * NPER) * ostr
                    + (size_t)po * (NXX * NYY) + xi * NYY + y;

    for (int n = 0; n < NPER; ++n) {
        // ---- issue all 16 loads back-to-back (vmcnt counts them; compute
        //      below waits fine-grained per first use) ----
        float2 ld[16];                            // static-indexed -> registers
#pragma unroll
        for (int c = 0; c < CIN; ++c) {
            const float* pc = xp + (size_t)(2 * c) * (SX * SY);
            ld[4 * c + 0] = *(const float2*)(pc);                 // d0 row0 {a,e}
            ld[4 * c + 1] = *(const float2*)(pc + SY);            // d0 row1 {b,f}
            ld[4 * c + 2] = *(const float2*)(pc + SX * SY);       // d1 row0 {a,e}
            ld[4 * c + 3] = *(const float2*)(pc + SX * SY + SY);  // d1 row1 {b,f}
        }

        float acc = bv;
#pragma unroll
        for (int c = 0; c < CIN; ++c) {
            const float a0 = ld[4 * c + 0].x, e0 = ld[4 * c + 0].y;
            const float b0 = ld[4 * c + 1].x, f0 = ld[4 * c + 1].y;
            const float a1 = ld[4 * c + 2].x, e1 = ld[4 * c + 2].y;
            const float b1 = ld[4 * c + 3].x, f1 = ld[4 * c + 3].y;
            const float ef00 = e0*f0, ef01 = e0*f1, ef10 = e1*f0, ef11 = e1*f1;
            const float ab00 = a0*b0, ab01 = a0*b1, ab10 = a1*b0, ab11 = a1*b1;
            const float* wq = wr[c];
            float t;
            t = ef00*wq[ 0] + ef01*wq[ 1] + ef10*wq[ 2] + ef11*wq[ 3];  acc += ab00 * t;
            t = ef00*wq[ 4] + ef01*wq[ 5] + ef10*wq[ 6] + ef11*wq[ 7];  acc += ab01 * t;
            t = ef00*wq[ 8] + ef01*wq[ 9] + ef10*wq[10] + ef11*wq[11];  acc += ab10 * t;
            t = ef00*wq[12] + ef01*wq[13] + ef10*wq[14] + ef11*wq[15];  acc += ab11 * t;
        }
        ob[0] = acc;                              // 2x128B coalesced per wave
        xp += nstr;
        ob += ostr;
    }
}

extern "C" void kernel_launch(void* const* d_in, const int* in_sizes, int n_in,
                              void* d_out, int out_size, void* d_ws, size_t ws_size,
                              hipStream_t stream) {
    const float* x    = (const float*)d_in[0];
    const float* w    = (const float*)d_in[1];
    const float* bias = (const float*)d_in[2];
    float* out = (float*)d_out;

    const int grid = NXX * (NYY / YTILE) * NSPLIT;  // 128*4*2 = 1024 blocks
    ttn_kernel<<<grid, 256, 0, stream>>>(x, w, bias, out);
}

// Round 6
// 281.436 us; speedup vs baseline: 1.0938x; 1.0938x over previous
//
#include <hip/hip_runtime.h>

// x: (64, 4, 2, 256, 256) f32 ; tensors: (4,4,128,128,2,2,2,2,2) f32 ;
// bias: (4,128,128,2) f32 ; out: (64,4,2,128,128) f32
// sx=sy=256 even -> ix1=2x+1, iy1=2y+1 (clamp inert).
#define NUMN 64
#define CIN 4
#define COUT 4
#define SX 256
#define SY 256
#define NXX 128
#define NYY 128
#define YTILE 32
#define NSPLIT 2
#define NPER (NUMN / NSPLIT)

// R10: R9 (direct coalesced float2 loads, no LDS, no barriers — counters
// proved coalescing is perfect: WRITE=output exactly, FETCH~93MB) + the piece
// R9 was missing: a 1-iteration register prefetch distance. R9 consumed its
// 16 loads in the same iteration it issued them -> latency-bound (VALUBusy
// 13%). Here two 16xfloat2 buffers double-buffer the x reads: while computing
// bufA(n), bufB(n+1)'s loads are in flight; the compiler's counted vmcnt
// before the bufB compute waits only on those loads (never a full drain).
// Hand-unrolled 2x so the rotation is register renaming, not v_mov chains.
// ~150 VGPR expected -> 3 waves/SIMD; latency hidden by ILP not TLP.
__device__ __forceinline__ void issue_loads(float2 ld[16], const float* p)
{
#pragma unroll
    for (int c = 0; c < CIN; ++c) {
        const float* pc = p + (size_t)(2 * c) * (SX * SY);
        ld[4 * c + 0] = *(const float2*)(pc);                 // d0 row0 {a,e}
        ld[4 * c + 1] = *(const float2*)(pc + SY);            // d0 row1 {b,f}
        ld[4 * c + 2] = *(const float2*)(pc + SX * SY);       // d1 row0 {a,e}
        ld[4 * c + 3] = *(const float2*)(pc + SX * SY + SY);  // d1 row1 {b,f}
    }
}

__device__ __forceinline__ float compute_patch(const float2 ld[16],
                                               const float wr[CIN][16],
                                               float bv)
{
    float acc = bv;
#pragma unroll
    for (int c = 0; c < CIN; ++c) {
        const float a0 = ld[4 * c + 0].x, e0 = ld[4 * c + 0].y;
        const float b0 = ld[4 * c + 1].x, f0 = ld[4 * c + 1].y;
        const float a1 = ld[4 * c + 2].x, e1 = ld[4 * c + 2].y;
        const float b1 = ld[4 * c + 3].x, f1 = ld[4 * c + 3].y;
        const float ef00 = e0*f0, ef01 = e0*f1, ef10 = e1*f0, ef11 = e1*f1;
        const float ab00 = a0*b0, ab01 = a0*b1, ab10 = a1*b0, ab11 = a1*b1;
        const float* wq = wr[c];
        float t;
        t = ef00*wq[ 0] + ef01*wq[ 1] + ef10*wq[ 2] + ef11*wq[ 3];  acc += ab00 * t;
        t = ef00*wq[ 4] + ef01*wq[ 5] + ef10*wq[ 6] + ef11*wq[ 7];  acc += ab01 * t;
        t = ef00*wq[ 8] + ef01*wq[ 9] + ef10*wq[10] + ef11*wq[11];  acc += ab10 * t;
        t = ef00*wq[12] + ef01*wq[13] + ef10*wq[14] + ef11*wq[15];  acc += ab11 * t;
    }
    return acc;
}

__global__ __launch_bounds__(256, 2)
void ttn_kernel(const float* __restrict__ x, const float* __restrict__ w,
                const float* __restrict__ bias, float* __restrict__ out)
{
    const int bid = blockIdx.x;
    const int xi = bid % NXX;
    const int yt = (bid / NXX) % (NYY / YTILE);
    const int ns = bid / (NXX * (NYY / YTILE));

    const int tid = threadIdx.x;
    const int yl  = tid & (YTILE - 1);
    const int po  = tid >> 5;                    // p*2 + o  (0..7)
    const int p   = po >> 1;
    const int o   = po & 1;
    const int y   = yt * YTILE + yl;

    // ---- weight preamble: wr[c][q], q = 8i+4j+2k+l (float4 loads) ----
    float wr[CIN][16];
#pragma unroll
    for (int c = 0; c < CIN; ++c) {
        const float4* wp4 = (const float4*)(w +
            ((size_t)(((c * COUT + p) * NXX + xi) * NYY + y)) * 32);
#pragma unroll
        for (int j = 0; j < 8; ++j) {
            const float4 v = wp4[j];
            wr[c][2 * j]     = o ? v.y : v.x;
            wr[c][2 * j + 1] = o ? v.w : v.z;
        }
    }
    const float bv = bias[(((p * NXX + xi) * NYY + y) * 2) + o];

    const size_t nstr = (size_t)CIN * 2 * SX * SY;
    const size_t ostr = (size_t)COUT * 2 * NXX * NYY;

    // per-lane x pointer at (n = ns*NPER, c=0, d=0, row 2xi, col 2y):
    // lanes yl=0..31 read consecutive float2s (256B/wave request); lanes
    // 32..63 (other o) read the same addresses -> TA coalescer dedups.
    const float* xb = x + (size_t)(ns * NPER) * nstr
                        + (size_t)(2 * xi) * SY + 2 * y;
    float* ob = out + (size_t)(ns * NPER) * ostr
                    + (size_t)po * (NXX * NYY) + xi * NYY + y;

    float2 bufA[16], bufB[16];
    issue_loads(bufA, xb);                       // n = 0

    for (int n = 0; n < NPER; n += 2) {
        // prefetch n+1 while computing n   (n+1 <= NPER-1 always: NPER even)
        issue_loads(bufB, xb + (size_t)(n + 1) * nstr);
        ob[(size_t)n * ostr] = compute_patch(bufA, wr, bv);

        // prefetch n+2 while computing n+1 (clamp at the tail; redundant
        // reload of the last plane is harmless)
        const int np = (n + 2 < NPER) ? (n + 2) : (NPER - 1);
        issue_loads(bufA, xb + (size_t)np * nstr);
        ob[(size_t)(n + 1) * ostr] = compute_patch(bufB, wr, bv);
    }
}

extern "C" void kernel_launch(void* const* d_in, const int* in_sizes, int n_in,
                              void* d_out, int out_size, void* d_ws, size_t ws_size,
                              hipStream_t stream) {
    const float* x    = (const float*)d_in[0];
    const float* w    = (const float*)d_in[1];
    const float* bias = (const float*)d_in[2];
    float* out = (float*)d_out;

    const int grid = NXX * (NYY / YTILE) * NSPLIT;  // 128*4*2 = 1024 blocks
    ttn_kernel<<<grid, 256, 0, stream>>>(x, w, bias, out);
}

// Round 7
// 249.925 us; speedup vs baseline: 1.2317x; 1.1261x over previous
//
#include <hip/hip_runtime.h>

// x: (64, 4, 2, 256, 256) f32 ; tensors: (4,4,128,128,2,2,2,2,2) f32 ;
// bias: (4,128,128,2) f32 ; out: (64,4,2,128,128) f32
// sx=sy=256 even -> ix1=2x+1, iy1=2y+1 (clamp inert).
#define NUMN 64
#define CIN 4
#define COUT 4
#define SX 256
#define SY 256
#define NXX 128
#define NYY 128
#define YTILE 32
#define NSPLIT 2
#define NPER (NUMN / NSPLIT)
#define NBUF 4
#define PLANE (SX * SY)             // floats per (c,d) plane
#define WBUF_FLOATS (NBUF * 1024)   // per-wave LDS ring: 4 slots x 4KB

// R11: wave-private global_load_lds pipeline, ZERO barriers.
// Session diagnosis: every register-based prefetch (R4/R8 P-rotation, R10
// bufA/bufB) was silently collapsed by the compiler's register-pressure
// scheduling (R10 VGPR=72 proves it: wr alone needs 64; the "double buffer"
// never existed in the asm). global_load_lds is the one prefetch the
// compiler cannot collapse: no dest VGPR, issue point = program point,
// completion gated only by our counted s_waitcnt vmcnt(N).
// Each wave stages its own 4KB window (4x 1KB gl_lds; dest is HW-defined
// wave-uniform-base + lane*16, which matches the R8-verified linear layout:
// lane l, chunk k -> lds float offset 4l + 256k = mc*64 + j0 with
// mc=(l>>4)+4k, j0=(l&15)*4). 4-slot ring, depth-3 in flight, no cross-wave
// data -> no s_barrier anywhere; waves free-run.
// vmcnt counting (in-order retirement, m135): at iter n's wait, ops newer
// than the 4th gl_lds(n) are >= 12 gl_lds (+ up to 3 stores); vmcnt(12) is
// exact at the prologue boundary and conservative (+stores) in steady state.
// Tail: re-stage plane NPER-1 into its own slot (idempotent bytes) to keep
// the count uniform -- skipping stages would break the vmcnt arithmetic.
__device__ __forceinline__ void stage4(const float* sp, float* dp)
{
#pragma unroll
    for (int k = 0; k < 4; ++k) {
        __builtin_amdgcn_global_load_lds(
            (const __attribute__((address_space(1))) void*)(sp + (size_t)k * 2 * PLANE),
            (__attribute__((address_space(3))) void*)(dp + k * 256),
            16, 0, 0);
    }
}

__global__ __launch_bounds__(256, 2)
void ttn_kernel(const float* __restrict__ x, const float* __restrict__ w,
                const float* __restrict__ bias, float* __restrict__ out)
{
    __shared__ float lds[4 * WBUF_FLOATS];       // 4 waves x 16KB = 64KB

    const int bid = blockIdx.x;
    const int xi = bid % NXX;
    const int yt = (bid / NXX) % (NYY / YTILE);
    const int ns = bid / (NXX * (NYY / YTILE));

    const int tid = threadIdx.x;
    const int wv  = tid >> 6;                    // wave 0..3
    const int l   = tid & 63;                    // lane
    const int yl  = tid & (YTILE - 1);
    const int po  = tid >> 5;                    // p*2 + o (wave wv holds 2wv, 2wv+1)
    const int p   = po >> 1;
    const int o   = po & 1;
    const int y   = yt * YTILE + yl;

    // ---- weight preamble: wr[c][q], q = 8i+4j+2k+l (float4 loads) ----
    float wr[CIN][16];
#pragma unroll
    for (int c = 0; c < CIN; ++c) {
        const float4* wp4 = (const float4*)(w +
            ((size_t)(((c * COUT + p) * NXX + xi) * NYY + y)) * 32);
#pragma unroll
        for (int j = 0; j < 8; ++j) {
            const float4 v = wp4[j];
            wr[c][2 * j]     = o ? v.y : v.x;
            wr[c][2 * j + 1] = o ? v.w : v.z;
        }
    }
    float bv = bias[(((p * NXX + xi) * NYY + y) * 2) + o];
    asm volatile("" : "+v"(bv));                 // force load+wait here, pre-drain

    const size_t nstr = (size_t)CIN * 2 * PLANE;
    const size_t ostr = (size_t)COUT * 2 * NXX * NYY;

    // staging lane map for gl_lds k: mc = (l>>4)+4k; prow = mc>>1 = (l>>4 >>1)+2k,
    // r = mc&1 = (l>>4)&1 (k-invariant); j0 = (l&15)*4 floats (16B units).
    const int mc0   = l >> 4;
    const int prow0 = mc0 >> 1;
    const int r0    = mc0 & 1;
    const int j0s   = (l & 15) * 4;

    const float* xs = x + (size_t)(ns * NPER) * nstr
                        + ((size_t)prow0 * SX + (2 * xi + r0)) * SY + yt * 64 + j0s;
    float* ob = out + (size_t)(ns * NPER) * ostr
                    + (size_t)po * (NXX * NYY) + xi * NYY + y;
    float* wbase = &lds[wv * WBUF_FLOATS];       // wave-private ring base (uniform)

    // all preamble VMEM retired -> vmcnt counting below is exact
    asm volatile("s_waitcnt vmcnt(0)" ::: "memory");

    stage4(xs,                       wbase);            // slot 0, n=0
    stage4(xs + 1 * nstr,            wbase + 1024);     // slot 1, n=1
    stage4(xs + 2 * nstr,            wbase + 2048);     // slot 2, n=2

    for (int n = 0; n < NPER; ++n) {
        // depth-3: issue stage for n+3 (clamped; idempotent at tail) BEFORE
        // the wait, so 12 gl_lds stay in flight across the compute.
        const int ns3 = (n + 3 < NPER) ? (n + 3) : (NPER - 1);
        stage4(xs + (size_t)ns3 * nstr, wbase + ((ns3 & (NBUF - 1)) << 10));

        // wait: everything older than the 12 newest gl_lds retired ->
        // slot n's 4 DMAs complete. Stores retire fast; counted, never 0.
        asm volatile("s_waitcnt vmcnt(12)" ::: "memory");

        const float2* b2 = (const float2*)(wbase + ((n & (NBUF - 1)) << 10));
        float acc = bv;
#pragma unroll
        for (int c = 0; c < CIN; ++c) {
            const float2 ae0 = b2[c * 128 +       yl];   // d0 row0 {a,e}
            const float2 bf0 = b2[c * 128 +  32 + yl];   // d0 row1 {b,f}
            const float2 ae1 = b2[c * 128 +  64 + yl];   // d1 row0 {a,e}
            const float2 bf1 = b2[c * 128 +  96 + yl];   // d1 row1 {b,f}
            const float a0 = ae0.x, e0 = ae0.y, b0 = bf0.x, f0 = bf0.y;
            const float a1 = ae1.x, e1 = ae1.y, b1 = bf1.x, f1 = bf1.y;
            const float ef00 = e0*f0, ef01 = e0*f1, ef10 = e1*f0, ef11 = e1*f1;
            const float ab00 = a0*b0, ab01 = a0*b1, ab10 = a1*b0, ab11 = a1*b1;
            const float* wq = wr[c];
            float t;
            t = ef00*wq[ 0] + ef01*wq[ 1] + ef10*wq[ 2] + ef11*wq[ 3];  acc += ab00 * t;
            t = ef00*wq[ 4] + ef01*wq[ 5] + ef10*wq[ 6] + ef11*wq[ 7];  acc += ab01 * t;
            t = ef00*wq[ 8] + ef01*wq[ 9] + ef10*wq[10] + ef11*wq[11];  acc += ab10 * t;
            t = ef00*wq[12] + ef01*wq[13] + ef10*wq[14] + ef11*wq[15];  acc += ab11 * t;
        }
        ob[(size_t)n * ostr] = acc;
        // slot-reuse safety: stage(n+3) targets slot (n+3)&3 = (n-1)&3, whose
        // ds_reads were consumed by compute(n-1) (lgkmcnt-drained) before
        // store(n-1), which precedes this iter's stage in program order.
    }
}

extern "C" void kernel_launch(void* const* d_in, const int* in_sizes, int n_in,
                              void* d_out, int out_size, void* d_ws, size_t ws_size,
                              hipStream_t stream) {
    const float* x    = (const float*)d_in[0];
    const float* w    = (const float*)d_in[1];
    const float* bias = (const float*)d_in[2];
    float* out = (float*)d_out;

    const int grid = NXX * (NYY / YTILE) * NSPLIT;  // 128*4*2 = 1024 blocks
    ttn_kernel<<<grid, 256, 0, stream>>>(x, w, bias, out);
}

// Round 8
// 236.757 us; speedup vs baseline: 1.3002x; 1.0556x over previous
//
#include <hip/hip_runtime.h>

// x: (64, 4, 2, 256, 256) f32 ; tensors: (4,4,128,128,2,2,2,2,2) f32 ;
// bias: (4,128,128,2) f32 ; out: (64,4,2,128,128) f32
// sx=sy=256 even -> ix1=2x+1, iy1=2y+1 (clamp inert).
#define NUMN 64
#define CIN 4
#define COUT 4
#define SX 256
#define SY 256
#define NXX 128
#define NYY 128
#define YTILE 8
#define NSPLIT 2
#define NPER (NUMN / NSPLIT)
#define PLANE (SX * SY)

// R12 = R5's shape x R11's mechanism.
// Diagnosis after 6 rounds: VALUBusy never exceeds ~31% in ANY structure, and
// occupancy never exceeds ~27% except R5's 1-wave WGs (41%). Per-wave iter has
// only ~250cy VALU; with <=8 waves/CU no amount of scheduling hides latency:
// the kernel is TLP-starved. R5 lost only to its collapsed register prefetch
// + syncthreads vmcnt(0) drain. So: 64-thread WGs (YTILE=8), grid 4096 =
// 16 WGs/CU resident (VGPR ~96, LDS 4KB both allow it), each wave staging its
// own 1KB/iter with ONE global_load_lds (uncollapsible: no dest VGPR) into a
// private 4-slot ring, depth-3 in flight, counted vmcnt, ZERO barriers.
// Kills R11's 4x staging redundancy (16KB->4KB unique per block-iter) and
// 16->2 VMEM instr per wave-iter. LDS reads are 8-lane broadcasts (lanes
// sharing yl) -> conflict-free.
// vmcnt ladder: at iter n the wait must leave exactly the ops newer than
// slot-n's gl_lds outstanding: n=0 ->3 (gl1,gl2,gl3), n=1 ->4 (+st0),
// n=2 ->5, n>=3 ->6 (3 gl + 3 st) — stores retire in-order in the same queue.
// Tail: clamped re-stage of plane NPER-1 (idempotent bytes, keeps count uniform).
__global__ __launch_bounds__(64, 4)
void ttn_kernel(const float* __restrict__ x, const float* __restrict__ w,
                const float* __restrict__ bias, float* __restrict__ out)
{
    __shared__ float lds[4 * 256];               // 4 slots x 1KB

    const int bid = blockIdx.x;
    const int xi = bid % NXX;
    const int yt = (bid / NXX) % (NYY / YTILE);
    const int ns = bid / (NXX * (NYY / YTILE));

    const int tid = threadIdx.x;                 // 0..63, one wave
    const int yl  = tid & (YTILE - 1);           // 0..7
    const int po  = tid >> 3;                    // p*2 + o (0..7)
    const int p   = po >> 1;
    const int o   = po & 1;
    const int y   = yt * YTILE + yl;

    // ---- weight preamble: wr[c][q], q = 8i+4j+2k+l (float4 loads) ----
    float wr[CIN][16];
#pragma unroll
    for (int c = 0; c < CIN; ++c) {
        const float4* wp4 = (const float4*)(w +
            ((size_t)(((c * COUT + p) * NXX + xi) * NYY + y)) * 32);
#pragma unroll
        for (int j = 0; j < 8; ++j) {
            const float4 v = wp4[j];
            wr[c][2 * j]     = o ? v.y : v.x;
            wr[c][2 * j + 1] = o ? v.w : v.z;
        }
    }
    const float bv = bias[(((p * NXX + xi) * NYY + y) * 2) + o];

    const size_t nstr = (size_t)CIN * 2 * PLANE;
    const size_t ostr = (size_t)COUT * 2 * NXX * NYY;

    // staging map: lane l -> chunk mc = l>>2 = c*4+d*2+r, 16B sub-offset
    // (l&3)*4 floats. gl_lds writes lane l at lds float offset 4l = 16*mc+j0,
    // i.e. chunk mc occupies floats [16mc,16mc+16) = cols yt*16..yt*16+15 of
    // plane (c*2+d), row 2xi+r. (HW: dest = uniform base + lane*16B; source
    // address is per-lane.)
    const int mc = tid >> 2;
    const int cd = mc >> 1;                      // c*2 + d  (plane index)
    const int rr = mc & 1;
    const int j0 = (tid & 3) * 4;

    const float* xs = x + (size_t)(ns * NPER) * nstr
                        + (size_t)cd * PLANE
                        + (size_t)(2 * xi + rr) * SY + yt * 16 + j0;
    float* ob = out + (size_t)(ns * NPER) * ostr
                    + (size_t)po * (NXX * NYY) + xi * NYY + y;
    float* lb = &lds[0];

    // drain preamble VMEM so the vmcnt ladder below counts exactly
    asm volatile("s_waitcnt vmcnt(0)" ::: "memory");

#define STAGE(nn, slot)                                                        \
    __builtin_amdgcn_global_load_lds(                                          \
        (const __attribute__((address_space(1))) void*)(xs + (size_t)(nn) * nstr), \
        (__attribute__((address_space(3))) void*)(lb + ((slot) << 8)), 16, 0, 0)

    STAGE(0, 0);
    STAGE(1, 1);
    STAGE(2, 2);

    for (int n = 0; n < NPER; ++n) {
        const int ns3 = (n + 3 < NPER) ? (n + 3) : (NPER - 1);
        STAGE(ns3, ns3 & 3);

        if      (n >= 3) asm volatile("s_waitcnt vmcnt(6)" ::: "memory");
        else if (n == 2) asm volatile("s_waitcnt vmcnt(5)" ::: "memory");
        else if (n == 1) asm volatile("s_waitcnt vmcnt(4)" ::: "memory");
        else             asm volatile("s_waitcnt vmcnt(3)" ::: "memory");

        const float2* b2 = (const float2*)(lb + ((n & 3) << 8));
        float acc = bv;
#pragma unroll
        for (int c = 0; c < CIN; ++c) {
            const float2 ae0 = b2[c * 32 +      yl];   // d0 row0 {a,e}
            const float2 bf0 = b2[c * 32 +  8 + yl];   // d0 row1 {b,f}
            const float2 ae1 = b2[c * 32 + 16 + yl];   // d1 row0 {a,e}
            const float2 bf1 = b2[c * 32 + 24 + yl];   // d1 row1 {b,f}
            const float a0 = ae0.x, e0 = ae0.y, b0 = bf0.x, f0 = bf0.y;
            const float a1 = ae1.x, e1 = ae1.y, b1 = bf1.x, f1 = bf1.y;
            const float ef00 = e0*f0, ef01 = e0*f1, ef10 = e1*f0, ef11 = e1*f1;
            const float ab00 = a0*b0, ab01 = a0*b1, ab10 = a1*b0, ab11 = a1*b1;
            const float* wq = wr[c];
            float t;
            t = ef00*wq[ 0] + ef01*wq[ 1] + ef10*wq[ 2] + ef11*wq[ 3];  acc += ab00 * t;
            t = ef00*wq[ 4] + ef01*wq[ 5] + ef10*wq[ 6] + ef11*wq[ 7];  acc += ab01 * t;
            t = ef00*wq[ 8] + ef01*wq[ 9] + ef10*wq[10] + ef11*wq[11];  acc += ab10 * t;
            t = ef00*wq[12] + ef01*wq[13] + ef10*wq[14] + ef11*wq[15];  acc += ab11 * t;
        }
        ob[(size_t)n * ostr] = acc;
        // ring safety: STAGE(n+3) writes slot (n-1)&3 whose ds_reads were
        // consumed by compute(n-1) (in-order wave, lgkmcnt-drained before use)
        // strictly before this iteration's STAGE issues.
    }
#undef STAGE
}

extern "C" void kernel_launch(void* const* d_in, const int* in_sizes, int n_in,
                              void* d_out, int out_size, void* d_ws, size_t ws_size,
                              hipStream_t stream) {
    const float* x    = (const float*)d_in[0];
    const float* w    = (const float*)d_in[1];
    const float* bias = (const float*)d_in[2];
    float* out = (float*)d_out;

    const int grid = NXX * (NYY / YTILE) * NSPLIT;  // 128*16*2 = 4096 blocks
    ttn_kernel<<<grid, 64, 0, stream>>>(x, w, bias, out);
}